// Round 1
// baseline (82.064 us; speedup 1.0000x reference)
//
#include <hip/hip_runtime.h>

// Standardization: x (2M, 20) fp32 -> reshape (2M, 2, 10), per-segment
// (length-10) mean/std normalization: (x - mean) / (std + eps), ddof=0.
// Pure memory-bound streaming op: 160 MB in + 160 MB out.
// One thread per ROW (20 floats = 80 B, 16B-aligned every row) so all
// global traffic is aligned dwordx4.

constexpr float EPS = 1e-7f;

__global__ __launch_bounds__(256) void stdz_kernel(const float* __restrict__ x,
                                                   float* __restrict__ out,
                                                   int nrows) {
    int row = blockIdx.x * 256 + threadIdx.x;
    if (row >= nrows) return;
    size_t base = (size_t)row * 20;

    const float4* __restrict__ xin = reinterpret_cast<const float4*>(x + base);
    float4 r0 = xin[0];
    float4 r1 = xin[1];
    float4 r2 = xin[2];
    float4 r3 = xin[3];
    float4 r4 = xin[4];

    float v[20] = {r0.x, r0.y, r0.z, r0.w,
                   r1.x, r1.y, r1.z, r1.w,
                   r2.x, r2.y, r2.z, r2.w,
                   r3.x, r3.y, r3.z, r3.w,
                   r4.x, r4.y, r4.z, r4.w};

#pragma unroll
    for (int s = 0; s < 2; ++s) {
        float sum = 0.0f;
#pragma unroll
        for (int j = 0; j < 10; ++j) sum += v[s * 10 + j];
        float mean = sum * 0.1f;

        float var = 0.0f;
#pragma unroll
        for (int j = 0; j < 10; ++j) {
            float d = v[s * 10 + j] - mean;
            var += d * d;
        }
        float inv = 1.0f / (sqrtf(var * 0.1f) + EPS);

#pragma unroll
        for (int j = 0; j < 10; ++j) v[s * 10 + j] = (v[s * 10 + j] - mean) * inv;
    }

    float4* __restrict__ o = reinterpret_cast<float4*>(out + base);
    o[0] = make_float4(v[0], v[1], v[2], v[3]);
    o[1] = make_float4(v[4], v[5], v[6], v[7]);
    o[2] = make_float4(v[8], v[9], v[10], v[11]);
    o[3] = make_float4(v[12], v[13], v[14], v[15]);
    o[4] = make_float4(v[16], v[17], v[18], v[19]);
}

extern "C" void kernel_launch(void* const* d_in, const int* in_sizes, int n_in,
                              void* d_out, int out_size, void* d_ws, size_t ws_size,
                              hipStream_t stream) {
    const float* x = (const float*)d_in[0];
    float* out = (float*)d_out;
    int nrows = in_sizes[0] / 20;  // 2,000,000
    int blocks = (nrows + 255) / 256;
    stdz_kernel<<<blocks, 256, 0, stream>>>(x, out, nrows);
}

// Round 2
// 62.036 us; speedup vs baseline: 1.3229x; 1.3229x over previous
//
#include <hip/hip_runtime.h>

// Standardization: x (2M, 20) fp32 -> (2M, 2, 10), per-length-10-segment
// (x - mean) / (pop_std + 1e-7).
//
// Memory-bound streaming op. Previous version did per-thread-row strided
// loads (80 B lane stride -> ~64 lines touched per wave-load -> address-
// divergence throttled VMEM to ~2.5 TB/s). This version stages through LDS:
// coalesced global <-> LDS transpose, row access in LDS with odd stride (21)
// so all row-wise b32 accesses are bank-conflict-free.

constexpr float EPS = 1e-7f;
constexpr int THREADS = 256;
constexpr int ROWS_PER_BLOCK = 256;   // one row per thread
constexpr int LDS_STRIDE = 21;        // 20 + 1 pad (odd => conflict-free)

__global__ __launch_bounds__(256) void stdz_kernel(const float* __restrict__ x,
                                                   float* __restrict__ out,
                                                   int nrows) {
    __shared__ float tile[ROWS_PER_BLOCK * LDS_STRIDE];  // 21504 B -> 7 blocks/CU

    const int t = threadIdx.x;
    const long long block_row0 = (long long)blockIdx.x * ROWS_PER_BLOCK;
    const long long total_f4 = (long long)nrows * 5;   // 20 floats = 5 float4 per row
    const long long base_f4 = block_row0 * 5;

    const float4* __restrict__ xin4 = reinterpret_cast<const float4*>(x);

    // ---- stage in: coalesced global float4 loads -> LDS (padded rows) ----
#pragma unroll
    for (int k = 0; k < 5; ++k) {
        long long g = base_f4 + (long long)(k * THREADS + t);
        if (g < total_f4) {
            float4 v = xin4[g];
            int idx = k * THREADS + t;       // float4 index within the tile
            int r = idx / 5;                 // row within tile
            int c = idx % 5;                 // float4 chunk within row
            float* p = &tile[r * LDS_STRIDE + c * 4];
            p[0] = v.x; p[1] = v.y; p[2] = v.z; p[3] = v.w;
        }
    }
    __syncthreads();

    // ---- per-row compute: thread t owns tile row t (exclusive, in-place) ----
    {
        long long row = block_row0 + t;
        if (row < nrows) {
            float* rp = &tile[t * LDS_STRIDE];
            float v[20];
#pragma unroll
            for (int j = 0; j < 20; ++j) v[j] = rp[j];

#pragma unroll
            for (int s = 0; s < 2; ++s) {
                float sum = 0.0f;
#pragma unroll
                for (int j = 0; j < 10; ++j) sum += v[s * 10 + j];
                float mean = sum * 0.1f;

                float var = 0.0f;
#pragma unroll
                for (int j = 0; j < 10; ++j) {
                    float d = v[s * 10 + j] - mean;
                    var += d * d;
                }
                float inv = 1.0f / (sqrtf(var * 0.1f) + EPS);

#pragma unroll
                for (int j = 0; j < 10; ++j) v[s * 10 + j] = (v[s * 10 + j] - mean) * inv;
            }

#pragma unroll
            for (int j = 0; j < 20; ++j) rp[j] = v[j];
        }
    }
    __syncthreads();

    // ---- stage out: LDS -> coalesced global float4 stores ----
    float4* __restrict__ o4 = reinterpret_cast<float4*>(out);
#pragma unroll
    for (int k = 0; k < 5; ++k) {
        long long g = base_f4 + (long long)(k * THREADS + t);
        if (g < total_f4) {
            int idx = k * THREADS + t;
            int r = idx / 5;
            int c = idx % 5;
            const float* p = &tile[r * LDS_STRIDE + c * 4];
            o4[g] = make_float4(p[0], p[1], p[2], p[3]);
        }
    }
}

extern "C" void kernel_launch(void* const* d_in, const int* in_sizes, int n_in,
                              void* d_out, int out_size, void* d_ws, size_t ws_size,
                              hipStream_t stream) {
    const float* x = (const float*)d_in[0];
    float* out = (float*)d_out;
    int nrows = in_sizes[0] / 20;  // 2,000,000
    int blocks = (nrows + ROWS_PER_BLOCK - 1) / ROWS_PER_BLOCK;
    stdz_kernel<<<blocks, THREADS, 0, stream>>>(x, out, nrows);
}

// Round 4
// 52.039 us; speedup vs baseline: 1.5770x; 1.1921x over previous
//
#include <hip/hip_runtime.h>

// Standardization: x (2M, 20) fp32 -> (2M, 2, 10), per-length-10-segment
// (x - mean) / (pop_std + 1e-7).
//
// Wave-synchronous version: each 64-lane wave owns a private 64-row LDS
// tile, so the global<->LDS transpose needs NO __syncthreads — intra-wave
// LDS ordering via s_waitcnt lgkmcnt(0) (DS ops are processed in wave
// issue order). Waves pipeline independently; no block-wide vmcnt(0)
// drains. Stores are nontemporal to keep the (L3-resident) input from
// being evicted by the write stream.
//
// NOTE: __builtin_nontemporal_store requires a NATIVE vector type, not
// HIP's float4 class -> use ext_vector_type(4).

constexpr float EPS = 1e-7f;
constexpr int THREADS = 256;
constexpr int ROWS_PER_WAVE = 64;
constexpr int WAVES_PER_BLOCK = 4;
constexpr int ROWS_PER_BLOCK = ROWS_PER_WAVE * WAVES_PER_BLOCK;  // 256
constexpr int LDS_STRIDE = 21;  // 20 + 1 pad (odd => row b32 access conflict-free)

typedef float f32x4 __attribute__((ext_vector_type(4)));

__global__ __launch_bounds__(256) void stdz_kernel(const float* __restrict__ x,
                                                   float* __restrict__ out,
                                                   int nrows) {
    __shared__ float tile[WAVES_PER_BLOCK][ROWS_PER_WAVE * LDS_STRIDE];  // 21504 B

    const int wave = threadIdx.x >> 6;
    const int lane = threadIdx.x & 63;
    float* __restrict__ wt = tile[wave];

    const long long wave_row0 =
        (long long)blockIdx.x * ROWS_PER_BLOCK + (long long)wave * ROWS_PER_WAVE;
    const long long total_f4 = (long long)nrows * 5;  // 5 float4 per row
    const long long base_f4 = wave_row0 * 5;          // 320 float4 per wave tile

    const f32x4* __restrict__ xin4 = reinterpret_cast<const f32x4*>(x);

    // ---- stage in: 5 coalesced wave loads (1 KB/instr) -> private LDS tile ----
#pragma unroll
    for (int k = 0; k < 5; ++k) {
        long long g = base_f4 + (long long)(k * ROWS_PER_WAVE + lane);
        if (g < total_f4) {
            f32x4 v = xin4[g];
            int idx = k * ROWS_PER_WAVE + lane;  // float4 index within tile
            int r = idx / 5;
            int c = idx - 5 * r;
            float* p = &wt[r * LDS_STRIDE + c * 4];
            p[0] = v.x; p[1] = v.y; p[2] = v.z; p[3] = v.w;
        }
    }
    asm volatile("s_waitcnt lgkmcnt(0)" ::: "memory");
    __builtin_amdgcn_wave_barrier();

    // ---- per-row compute: lane owns tile row `lane` (in-place) ----
    {
        long long row = wave_row0 + lane;
        if (row < nrows) {
            float* rp = &wt[lane * LDS_STRIDE];
            float v[20];
#pragma unroll
            for (int j = 0; j < 20; ++j) v[j] = rp[j];

#pragma unroll
            for (int s = 0; s < 2; ++s) {
                float sum = 0.0f;
#pragma unroll
                for (int j = 0; j < 10; ++j) sum += v[s * 10 + j];
                float mean = sum * 0.1f;

                float var = 0.0f;
#pragma unroll
                for (int j = 0; j < 10; ++j) {
                    float d = v[s * 10 + j] - mean;
                    var += d * d;
                }
                float inv = 1.0f / (sqrtf(var * 0.1f) + EPS);

#pragma unroll
                for (int j = 0; j < 10; ++j) v[s * 10 + j] = (v[s * 10 + j] - mean) * inv;
            }

#pragma unroll
            for (int j = 0; j < 20; ++j) rp[j] = v[j];
        }
    }
    asm volatile("s_waitcnt lgkmcnt(0)" ::: "memory");
    __builtin_amdgcn_wave_barrier();

    // ---- stage out: private LDS tile -> 5 coalesced nontemporal wave stores ----
    f32x4* __restrict__ o4 = reinterpret_cast<f32x4*>(out);
#pragma unroll
    for (int k = 0; k < 5; ++k) {
        long long g = base_f4 + (long long)(k * ROWS_PER_WAVE + lane);
        if (g < total_f4) {
            int idx = k * ROWS_PER_WAVE + lane;
            int r = idx / 5;
            int c = idx - 5 * r;
            const float* p = &wt[r * LDS_STRIDE + c * 4];
            f32x4 v = {p[0], p[1], p[2], p[3]};
            __builtin_nontemporal_store(v, &o4[g]);
        }
    }
}

extern "C" void kernel_launch(void* const* d_in, const int* in_sizes, int n_in,
                              void* d_out, int out_size, void* d_ws, size_t ws_size,
                              hipStream_t stream) {
    const float* x = (const float*)d_in[0];
    float* out = (float*)d_out;
    int nrows = in_sizes[0] / 20;  // 2,000,000
    int blocks = (nrows + ROWS_PER_BLOCK - 1) / ROWS_PER_BLOCK;
    stdz_kernel<<<blocks, THREADS, 0, stream>>>(x, out, nrows);
}

// Round 5
// 51.636 us; speedup vs baseline: 1.5893x; 1.0078x over previous
//
#include <hip/hip_runtime.h>

// Standardization: x (2M, 20) fp32 -> (2M, 2, 10), per-length-10-segment
// (x - mean) / (pop_std + 1e-7).
//
// Wave-synchronous LDS transpose (no __syncthreads; intra-wave DS ordering
// via s_waitcnt lgkmcnt(0) + wave_barrier). This revision replaces the
// stride-21 scalar-b32 tile (80 ds ops/thread) with an UNPADDED linear tile
// accessed entirely as 16B-aligned ds_{read,write}_b128 (20 ds ops/thread),
// made bank-conflict-free by XOR-swizzling the float4 slot index:
//   slot' = slot ^ ((slot >> 3) & 7)
// For every access family here (stage: s=k*64+lane; row: s=5*lane+c),
// s mod 64 covers all residues, so (s&7)^((s>>3)&7) is uniform over the 8
// bank-quads -> each wave b128 op runs at the 8-lanes-per-quad HW floor.

constexpr float EPS = 1e-7f;
constexpr int THREADS = 256;
constexpr int ROWS_PER_WAVE = 64;
constexpr int WAVES_PER_BLOCK = 4;
constexpr int ROWS_PER_BLOCK = ROWS_PER_WAVE * WAVES_PER_BLOCK;  // 256
constexpr int SLOTS_PER_WAVE = ROWS_PER_WAVE * 5;                // 320 float4

typedef float f32x4 __attribute__((ext_vector_type(4)));

__global__ __launch_bounds__(256) void stdz_kernel(const float* __restrict__ x,
                                                   float* __restrict__ out,
                                                   int nrows) {
    // 320 f32x4 * 16 B * 4 waves = 20480 B -> 8 blocks/CU (LDS-limited none)
    __shared__ f32x4 tile[WAVES_PER_BLOCK][SLOTS_PER_WAVE];

    const int wave = threadIdx.x >> 6;
    const int lane = threadIdx.x & 63;
    f32x4* __restrict__ wt = tile[wave];

    const int swz_lane = (lane >> 3) & 7;  // stage-phase XOR term (k-invariant)

    const long long wave_row0 =
        (long long)blockIdx.x * ROWS_PER_BLOCK + (long long)wave * ROWS_PER_WAVE;
    const long long total_f4 = (long long)nrows * 5;  // 5 float4 per row
    const long long base_f4 = wave_row0 * 5;          // 320 float4 per wave tile

    const f32x4* __restrict__ xin4 = reinterpret_cast<const f32x4*>(x);

    // ---- stage in: 5 coalesced wave loads -> swizzled linear tile ----
#pragma unroll
    for (int k = 0; k < 5; ++k) {
        long long g = base_f4 + (long long)(k * ROWS_PER_WAVE + lane);
        if (g < total_f4) {
            f32x4 v = xin4[g];
            int f = k * ROWS_PER_WAVE + lane;
            wt[f ^ swz_lane] = v;  // ds_write_b128, conflict-free
        }
    }
    asm volatile("s_waitcnt lgkmcnt(0)" ::: "memory");
    __builtin_amdgcn_wave_barrier();

    // ---- per-row compute: lane owns row `lane` (5 b128 reads / 5 writes) ----
    {
        long long row = wave_row0 + lane;
        if (row < nrows) {
            float v[20];
#pragma unroll
            for (int c = 0; c < 5; ++c) {
                int s = 5 * lane + c;
                f32x4 q = wt[s ^ ((s >> 3) & 7)];  // ds_read_b128, conflict-free
                v[4 * c + 0] = q.x; v[4 * c + 1] = q.y;
                v[4 * c + 2] = q.z; v[4 * c + 3] = q.w;
            }

#pragma unroll
            for (int s = 0; s < 2; ++s) {
                float sum = 0.0f;
#pragma unroll
                for (int j = 0; j < 10; ++j) sum += v[s * 10 + j];
                float mean = sum * 0.1f;

                float var = 0.0f;
#pragma unroll
                for (int j = 0; j < 10; ++j) {
                    float d = v[s * 10 + j] - mean;
                    var += d * d;
                }
                float inv = 1.0f / (sqrtf(var * 0.1f) + EPS);

#pragma unroll
                for (int j = 0; j < 10; ++j) v[s * 10 + j] = (v[s * 10 + j] - mean) * inv;
            }

#pragma unroll
            for (int c = 0; c < 5; ++c) {
                int s = 5 * lane + c;
                f32x4 q = {v[4 * c + 0], v[4 * c + 1], v[4 * c + 2], v[4 * c + 3]};
                wt[s ^ ((s >> 3) & 7)] = q;  // ds_write_b128, conflict-free
            }
        }
    }
    asm volatile("s_waitcnt lgkmcnt(0)" ::: "memory");
    __builtin_amdgcn_wave_barrier();

    // ---- stage out: swizzled tile -> 5 coalesced nontemporal wave stores ----
    f32x4* __restrict__ o4 = reinterpret_cast<f32x4*>(out);
#pragma unroll
    for (int k = 0; k < 5; ++k) {
        long long g = base_f4 + (long long)(k * ROWS_PER_WAVE + lane);
        if (g < total_f4) {
            int f = k * ROWS_PER_WAVE + lane;
            f32x4 v = wt[f ^ swz_lane];  // ds_read_b128, conflict-free
            __builtin_nontemporal_store(v, &o4[g]);
        }
    }
}

extern "C" void kernel_launch(void* const* d_in, const int* in_sizes, int n_in,
                              void* d_out, int out_size, void* d_ws, size_t ws_size,
                              hipStream_t stream) {
    const float* x = (const float*)d_in[0];
    float* out = (float*)d_out;
    int nrows = in_sizes[0] / 20;  // 2,000,000
    int blocks = (nrows + ROWS_PER_BLOCK - 1) / ROWS_PER_BLOCK;
    stdz_kernel<<<blocks, THREADS, 0, stream>>>(x, out, nrows);
}